// Round 8
// baseline (450.018 us; speedup 1.0000x reference)
//
#include <hip/hip_runtime.h>
#include <math.h>

namespace {

constexpr int BT  = 8 * 4096;   // 32768 tokens
constexpr int DIM = 1024;       // model dim
constexpr int NE  = 64;         // experts
constexpr int NS  = 8;          // slots per expert
constexpr int NP  = NE * NS;    // 512 total slots
constexpr int HID = 256;

typedef float f32x4 __attribute__((ext_vector_type(4)));
typedef __bf16 bf16x8 __attribute__((ext_vector_type(8)));
typedef short s16x8 __attribute__((ext_vector_type(8)));

__device__ __forceinline__ ushort f2bf(float x) {
  union { float f; unsigned u; } a; a.f = x;
  unsigned r = a.u + 0x7FFFu + ((a.u >> 16) & 1u);  // RNE
  return (ushort)(r >> 16);
}
__device__ __forceinline__ float bf2f(ushort u) {
  union { unsigned u; float f; } a; a.u = (unsigned)u << 16;
  return a.f;
}

__device__ __forceinline__ void gload16(const void* g, void* l) {
  __builtin_amdgcn_global_load_lds(
      (const __attribute__((address_space(1))) void*)g,
      (__attribute__((address_space(3))) void*)l, 16, 0, 0);
}

// ---------------------------------------------------------------------------
// bf16 MFMA GEMM: C[M][N] = A[M][K](bf16 rm) @ Bt[N][K](bf16)^T
// 128x128 tile, BK=32, 4 waves 2x2. T1 XCD-chunked swizzle.
// T4 counted-vmcnt pipeline with COMPILE-TIME-CONSTANT buffers: four separate
// __shared__ objects + 2x-unrolled K-loop. With constant buffer identities the
// waitcnt pass can attribute each LDS-DMA write to a distinct object and does
// NOT insert a conservative vmcnt(0) before the ds_reads (the round-6 runtime
// `cur` index forced exactly that, nullifying the counted wait). Tile t+1's
// loads stay in flight across compute(t).
// ---------------------------------------------------------------------------
template <bool ATOMIC, bool OBF>
__global__ __launch_bounds__(256) void k_gemm(const ushort* __restrict__ A,
                                              const ushort* __restrict__ Bt,
                                              void* __restrict__ Cv,
                                              int K, int N, int kchunk) {
  __shared__ __align__(16) ushort As0[128 * 32];
  __shared__ __align__(16) ushort Bs0[128 * 32];
  __shared__ __align__(16) ushort As1[128 * 32];
  __shared__ __align__(16) ushort Bs1[128 * 32];
  const int tid = threadIdx.x;
  const int wid = tid >> 6;
  const int lane = tid & 63;

  // T1 XCD-chunked swizzle (bijective: nwg % 8 == 0)
  const int gx = gridDim.x, gy = gridDim.y;
  int wg = (blockIdx.z * gy + blockIdx.y) * gx + blockIdx.x;
  const int nwg = gx * gy * gridDim.z;
  wg = (wg & 7) * (nwg >> 3) + (wg >> 3);
  const int bx = wg % gx;
  const int rest = wg / gx;
  const int by = rest % gy;
  const int bz = rest / gy;

  const int n0 = bx * 128;
  const int m0 = by * 128;
  const int kb = bz * kchunk;

  const int srow = tid >> 2;
  const int skoff = (tid & 3) * 8;
  const int woff = wid * 512;  // wave's linear staging quarter (ushorts)

  const int wr = (wid >> 1) * 64;
  const int wc = (wid & 1) * 64;
  const int fr = lane & 15;
  const int fq = lane >> 4;

  f32x4 acc[4][4];
#pragma unroll
  for (int i = 0; i < 4; ++i)
#pragma unroll
    for (int j = 0; j < 4; ++j) acc[i][j] = (f32x4){0.f, 0.f, 0.f, 0.f};

  const ushort* Arow0 = A + (size_t)(m0 + srow) * K + skoff;
  const ushort* Arow1 = A + (size_t)(m0 + 64 + srow) * K + skoff;
  const ushort* Brow0 = Bt + (size_t)(n0 + srow) * K + skoff;
  const ushort* Brow1 = Bt + (size_t)(n0 + 64 + srow) * K + skoff;

#define STAGE(as_, bs_, kk)                       \
  do {                                            \
    gload16(Arow0 + (kk), (as_) + woff);          \
    gload16(Arow1 + (kk), (as_) + woff + 2048);   \
    gload16(Brow0 + (kk), (bs_) + woff);          \
    gload16(Brow1 + (kk), (bs_) + woff + 2048);   \
  } while (0)

#define COMPUTE(Ab, Bb)                                                          \
  do {                                                                           \
    bf16x8 af[4], bfr[4];                                                        \
    _Pragma("unroll") for (int m = 0; m < 4; ++m)                                \
      af[m] = __builtin_bit_cast(bf16x8,                                         \
          *(const s16x8*)((Ab) + (size_t)(wr + m * 16 + fr) * 32 + fq * 8));     \
    _Pragma("unroll") for (int n = 0; n < 4; ++n)                                \
      bfr[n] = __builtin_bit_cast(bf16x8,                                        \
          *(const s16x8*)((Bb) + (size_t)(wc + n * 16 + fr) * 32 + fq * 8));     \
    _Pragma("unroll") for (int m = 0; m < 4; ++m)                                \
      _Pragma("unroll") for (int n = 0; n < 4; ++n)                              \
        acc[m][n] = __builtin_amdgcn_mfma_f32_16x16x32_bf16(af[m], bfr[n],       \
                                                            acc[m][n], 0, 0, 0); \
  } while (0)

  const int nt = kchunk / 32;  // even for all call sites (32 / 64 / 16)
  STAGE(As0, Bs0, kb);
  for (int t = 0; t < nt; t += 2) {
    // -- half A: stage tile t+1 -> buf1, compute tile t from buf0 --
    STAGE(As1, Bs1, kb + (t + 1) * 32);
    asm volatile("s_waitcnt vmcnt(4)" ::: "memory");  // tile t landed; t+1 in flight
    __builtin_amdgcn_sched_barrier(0);
    __builtin_amdgcn_s_barrier();
    __builtin_amdgcn_sched_barrier(0);
    COMPUTE(As0, Bs0);
    __builtin_amdgcn_sched_barrier(0);
    __builtin_amdgcn_s_barrier();  // all waves done reading buf0
    __builtin_amdgcn_sched_barrier(0);
    // -- half B: stage tile t+2 -> buf0, compute tile t+1 from buf1 --
    if (t + 2 < nt) {
      STAGE(As0, Bs0, kb + (t + 2) * 32);
      asm volatile("s_waitcnt vmcnt(4)" ::: "memory");
    } else {
      asm volatile("s_waitcnt vmcnt(0)" ::: "memory");
    }
    __builtin_amdgcn_sched_barrier(0);
    __builtin_amdgcn_s_barrier();
    __builtin_amdgcn_sched_barrier(0);
    COMPUTE(As1, Bs1);
    __builtin_amdgcn_sched_barrier(0);
    __builtin_amdgcn_s_barrier();  // all waves done reading buf1
    __builtin_amdgcn_sched_barrier(0);
  }
#undef STAGE
#undef COMPUTE

  // C/D layout: col = lane&15, row = (lane>>4)*4 + reg   [m89-verified]
  if (OBF) {
    ushort* Cb = (ushort*)Cv + (size_t)(m0 + wr + fq * 4) * N + n0 + wc + fr;
#pragma unroll
    for (int m = 0; m < 4; ++m)
#pragma unroll
      for (int n = 0; n < 4; ++n)
#pragma unroll
        for (int r = 0; r < 4; ++r)
          Cb[(size_t)(m * 16 + r) * N + n * 16] = f2bf(acc[m][n][r]);
  } else {
    float* Cb = (float*)Cv + (size_t)(m0 + wr + fq * 4) * N + n0 + wc + fr;
#pragma unroll
    for (int m = 0; m < 4; ++m)
#pragma unroll
      for (int n = 0; n < 4; ++n)
#pragma unroll
        for (int r = 0; r < 4; ++r) {
          float* p = Cb + (size_t)(m * 16 + r) * N + n * 16;
          if (ATOMIC) atomicAdd(p, acc[m][n][r]);
          else *p = acc[m][n][r];
        }
  }
}

// ---------------------------------------------------------------------------
// fp32 [R][C] -> bf16 rowmajor and/or bf16 transposed, 64x64 tiles.
// ---------------------------------------------------------------------------
template <bool ROWM, bool TRANSP>
__global__ __launch_bounds__(256) void k_cvt(const float* __restrict__ X,
                                             ushort* __restrict__ Yrm,
                                             ushort* __restrict__ Yt,
                                             int Rr, int Cc) {
  __shared__ ushort tT[64][66];
  const int tid = threadIdx.x;
  const int r0 = blockIdx.x * 64, c0 = blockIdx.y * 64;
#pragma unroll
  for (int i = 0; i < 4; ++i) {
    const int idx = i * 256 + tid;
    const int r = idx >> 4, c4 = (idx & 15) * 4;
    float4 v = *(const float4*)(X + (size_t)(r0 + r) * Cc + c0 + c4);
    ushort u0 = f2bf(v.x), u1 = f2bf(v.y), u2 = f2bf(v.z), u3 = f2bf(v.w);
    if (ROWM) {
      ushort4 o = make_ushort4(u0, u1, u2, u3);
      *(ushort4*)(Yrm + (size_t)(r0 + r) * Cc + c0 + c4) = o;
    }
    if (TRANSP) {
      tT[c4 + 0][r] = u0; tT[c4 + 1][r] = u1;
      tT[c4 + 2][r] = u2; tT[c4 + 3][r] = u3;
    }
  }
  if (TRANSP) {
    __syncthreads();
#pragma unroll
    for (int i = 0; i < 2; ++i) {
      const int idx = i * 256 + tid;
      const int c = idx >> 3, r8 = (idx & 7) * 8;
      s16x8 o;
#pragma unroll
      for (int j = 0; j < 8; ++j) o[j] = (short)tT[c][r8 + j];
      *(s16x8*)(Yt + (size_t)(c0 + c) * Rr + r0 + r8) = o;
    }
  }
}

// ---------------------------------------------------------------------------
// Column softmax stats over bf16 mat. Block: 256 rows x all 512 cols.
// ---------------------------------------------------------------------------
__global__ __launch_bounds__(256) void k_colpart(const ushort* __restrict__ mat,
                                                 float* __restrict__ pm,
                                                 float* __restrict__ pz) {
  const int c8 = (threadIdx.x & 63) * 8;
  const int rq = threadIdx.x >> 6;
  const int r0 = blockIdx.x * 256;
  float m[8], z[8];
#pragma unroll
  for (int j = 0; j < 8; ++j) { m[j] = -INFINITY; z[j] = 0.f; }
  for (int r = r0 + rq; r < r0 + 256; r += 4) {
    s16x8 v = *(const s16x8*)(mat + (size_t)r * NP + c8);
#pragma unroll
    for (int j = 0; j < 8; ++j) {
      float f = bf2f((ushort)v[j]);
      float mm = fmaxf(m[j], f);
      z[j] = z[j] * __expf(m[j] - mm) + __expf(f - mm);
      m[j] = mm;
    }
  }
  __shared__ float sm[4][NP], sz[4][NP];
#pragma unroll
  for (int j = 0; j < 8; ++j) { sm[rq][c8 + j] = m[j]; sz[rq][c8 + j] = z[j]; }
  __syncthreads();
  if (rq == 0) {
#pragma unroll
    for (int j = 0; j < 8; ++j) {
      float mj = m[j], zj = z[j];
      for (int q = 1; q < 4; ++q) {
        float m2 = sm[q][c8 + j], z2 = sz[q][c8 + j];
        float mm = fmaxf(mj, m2);
        zj = zj * __expf(mj - mm) + z2 * __expf(m2 - mm);
        mj = mm;
      }
      pm[(size_t)blockIdx.x * NP + c8 + j] = mj;
      pz[(size_t)blockIdx.x * NP + c8 + j] = zj;
    }
  }
}

__global__ void k_colfinal(const float* __restrict__ pm, const float* __restrict__ pz,
                           float* __restrict__ colM, float* __restrict__ colIZ) {
  const int c = threadIdx.x;  // <<<1, NP>>>
  float m = -INFINITY, z = 0.f;
  for (int q = 0; q < BT / 256; ++q) {
    float m2 = pm[(size_t)q * NP + c], z2 = pz[(size_t)q * NP + c];
    float mm = fmaxf(m, m2);
    z = z * __expf(m - mm) + z2 * __expf(m2 - mm);
    m = mm;
  }
  colM[c] = m;
  colIZ[c] = 1.f / z;
}

// ---------------------------------------------------------------------------
// Row softmax stats over bf16 mat: one wave per token.
// ---------------------------------------------------------------------------
__global__ __launch_bounds__(256) void k_rowstats(const ushort* __restrict__ mat,
                                                  float* __restrict__ rowM,
                                                  float* __restrict__ rowIZ) {
  const int w = threadIdx.x >> 6;
  const int lane = threadIdx.x & 63;
  const int t = blockIdx.x * 4 + w;
  s16x8 v = *(const s16x8*)(mat + (size_t)t * NP + lane * 8);
  float f[8];
#pragma unroll
  for (int j = 0; j < 8; ++j) f[j] = bf2f((ushort)v[j]);
  float m = f[0];
#pragma unroll
  for (int j = 1; j < 8; ++j) m = fmaxf(m, f[j]);
#pragma unroll
  for (int o = 32; o; o >>= 1) m = fmaxf(m, __shfl_xor(m, o));
  float s = 0.f;
#pragma unroll
  for (int j = 0; j < 8; ++j) s += __expf(f[j] - m);
#pragma unroll
  for (int o = 32; o; o >>= 1) s += __shfl_xor(s, o);
  if (lane == 0) {
    rowM[t] = m;
    rowIZ[t] = 1.f / s;
  }
}

// ---------------------------------------------------------------------------
// Probabilities in bf16 from bf16 mat: Pc[t][s] and Pt[s][t]. 64x64 tiles.
// ---------------------------------------------------------------------------
__global__ __launch_bounds__(256) void k_probs(const ushort* __restrict__ mat,
                                               const float* __restrict__ colM,
                                               const float* __restrict__ colIZ,
                                               const float* __restrict__ rowM,
                                               const float* __restrict__ rowIZ,
                                               ushort* __restrict__ Pc,
                                               ushort* __restrict__ Pt) {
  __shared__ ushort tT[64][66];
  __shared__ float cm[64], cz[64], rm[64], rz[64];
  const int tid = threadIdx.x;
  const int t0 = blockIdx.x * 64, s0 = blockIdx.y * 64;
  if (tid < 64) {
    cm[tid] = colM[s0 + tid]; cz[tid] = colIZ[s0 + tid];
    rm[tid] = rowM[t0 + tid]; rz[tid] = rowIZ[t0 + tid];
  }
  __syncthreads();
#pragma unroll
  for (int i = 0; i < 2; ++i) {
    const int idx = i * 256 + tid;
    const int r = idx >> 3, c8 = (idx & 7) * 8;
    s16x8 v = *(const s16x8*)(mat + (size_t)(t0 + r) * NP + s0 + c8);
    const float mr = rm[r], zr = rz[r];
    s16x8 oc;
#pragma unroll
    for (int j = 0; j < 8; ++j) {
      float f = bf2f((ushort)v[j]);
      oc[j] = (short)f2bf(__expf(f - mr) * zr);
      tT[c8 + j][r] = f2bf(__expf(f - cm[c8 + j]) * cz[c8 + j]);
    }
    *(s16x8*)(Pc + (size_t)(t0 + r) * NP + s0 + c8) = oc;
  }
  __syncthreads();
#pragma unroll
  for (int i = 0; i < 2; ++i) {
    const int idx = i * 256 + tid;
    const int c = idx >> 3, r8 = (idx & 7) * 8;
    s16x8 o;
#pragma unroll
    for (int j = 0; j < 8; ++j) o[j] = (short)tT[c][r8 + j];
    *(s16x8*)(Pt + (size_t)(s0 + c) * BT + t0 + r8) = o;
  }
}

// ---------------------------------------------------------------------------
// Expert MLP layer (fp32, weight-streaming, memory-bound)
// ---------------------------------------------------------------------------
template <int K, int N, bool RELU>
__global__ __launch_bounds__(256) void k_mlp(const float* __restrict__ X,
                                             const float* __restrict__ W,
                                             const float* __restrict__ bias,
                                             float* __restrict__ Y) {
  __shared__ float xs[NS * K];
  const int tid = threadIdx.x;
  const int e = blockIdx.x;
  const float4* src = (const float4*)(X + (size_t)e * NS * K);
  float4* dst = (float4*)xs;
  constexpr int NV = (NS * K) / (4 * 256);
#pragma unroll
  for (int i = 0; i < NV; ++i) dst[tid + i * 256] = src[tid + i * 256];
  __syncthreads();
  const int j = blockIdx.y * 64 + (tid & 63);
  const int pr = tid >> 6;
  const float* w = W + (size_t)e * K * N + j;
  const float* x0 = xs + pr * K;
  const float* x1 = xs + (pr + 4) * K;
  float a0 = 0.f, a1 = 0.f;
#pragma unroll 8
  for (int k = 0; k < K; ++k) {
    float wv = w[(size_t)k * N];
    a0 += x0[k] * wv;
    a1 += x1[k] * wv;
  }
  const float bb = bias[(size_t)e * N + j];
  a0 += bb;
  a1 += bb;
  if (RELU) {
    a0 = fmaxf(a0, 0.f);
    a1 = fmaxf(a1, 0.f);
  }
  Y[((size_t)e * NS + pr) * N + j] = a0;
  Y[((size_t)e * NS + pr + 4) * N + j] = a1;
}

}  // namespace

extern "C" void kernel_launch(void* const* d_in, const int* in_sizes, int n_in,
                              void* d_out, int out_size, void* d_ws, size_t ws_size,
                              hipStream_t stream) {
  const float* tokens = (const float*)d_in[0];  // [BT, DIM]
  const float* em     = (const float*)d_in[1];  // [DIM, NP]
  const float* W1     = (const float*)d_in[2];
  const float* b1     = (const float*)d_in[3];
  const float* W2     = (const float*)d_in[4];
  const float* b2     = (const float*)d_in[5];
  const float* W3     = (const float*)d_in[6];
  const float* b3     = (const float*)d_in[7];
  float* out = (float*)d_out;

  char* w = (char*)d_ws;
  ushort* matb      = (ushort*)w; w += (size_t)BT * NP * 2;    // 32MB bf16 logits
  ushort* tokens_bf = (ushort*)w; w += (size_t)BT * DIM * 2;   // 64MB
  ushort* tokT      = (ushort*)w; w += (size_t)DIM * BT * 2;   // 64MB
  ushort* Pt        = (ushort*)w; w += (size_t)NP * BT * 2;    // 33.5MB
  ushort* Pc        = (ushort*)w; w += (size_t)BT * NP * 2;    // 33.5MB
  ushort* emT       = (ushort*)w; w += (size_t)NP * DIM * 2;
  ushort* yhatT     = (ushort*)w; w += (size_t)DIM * NP * 2;
  float*  pm        = (float*)w;  w += (size_t)(BT / 256) * NP * 4;
  float*  pz        = (float*)w;  w += (size_t)(BT / 256) * NP * 4;
  float*  colM      = (float*)w;  w += NP * 4;
  float*  colIZ     = (float*)w;  w += NP * 4;
  float*  rowM      = (float*)w;  w += BT * 4;
  float*  rowIZ     = (float*)w;  w += BT * 4;
  float*  xhat      = (float*)w;  w += (size_t)NP * DIM * 4;
  float*  h1        = (float*)w;  w += (size_t)NP * HID * 4;
  float*  h2        = (float*)w;  w += (size_t)NP * HID * 4;
  float*  yhat      = (float*)w;  w += (size_t)NP * DIM * 4;
  (void)ws_size; (void)in_sizes; (void)n_in; (void)out_size;

  // prep: one pass over fp32 tokens -> rowmajor bf16 + transposed bf16
  k_cvt<true, true><<<dim3(BT / 64, DIM / 64), 256, 0, stream>>>(tokens, tokens_bf, tokT, BT, DIM);
  k_cvt<false, true><<<dim3(DIM / 64, NP / 64), 256, 0, stream>>>(em, nullptr, emT, DIM, NP);
  // 1. routing logits (bf16 out), T1-swizzled, const-buffer counted-vmcnt pipeline
  k_gemm<false, true><<<dim3(NP / 128, BT / 128, 1), 256, 0, stream>>>(tokens_bf, emT, matb, DIM, NP, DIM);
  // 2. softmax stats
  k_colpart<<<BT / 256, 256, 0, stream>>>(matb, pm, pz);
  k_colfinal<<<1, NP, 0, stream>>>(pm, pz, colM, colIZ);
  k_rowstats<<<BT / 4, 256, 0, stream>>>(matb, rowM, rowIZ);
  // 3. probabilities in bf16 (Pc rowmajor, Pt transposed)
  k_probs<<<dim3(BT / 64, NP / 64), 256, 0, stream>>>(matb, colM, colIZ, rowM, rowIZ, Pc, Pt);
  // 4. dispatch: xhat = Pt @ tokens  (split-K 16, fp32 atomics), T1+T4
  hipMemsetAsync(xhat, 0, (size_t)NP * DIM * 4, stream);
  k_gemm<true, false><<<dim3(DIM / 128, NP / 128, 16), 256, 0, stream>>>(Pt, tokT, xhat, BT, DIM, BT / 16);
  // 5. expert MLPs (fp32)
  k_mlp<DIM, HID, true><<<dim3(NE, HID / 64), 256, 0, stream>>>(xhat, W1, b1, h1);
  k_mlp<HID, HID, true><<<dim3(NE, HID / 64), 256, 0, stream>>>(h1, W2, b2, h2);
  k_mlp<HID, DIM, false><<<dim3(NE, DIM / 64), 256, 0, stream>>>(h2, W3, b3, yhat);
  k_cvt<false, true><<<dim3(NP / 64, DIM / 64), 256, 0, stream>>>(yhat, nullptr, yhatT, NP, DIM);
  // 6. combine: out = Pc @ yhat, T1+T4
  k_gemm<false, false><<<dim3(DIM / 128, BT / 128, 1), 256, 0, stream>>>(Pc, yhatT, out, NP, DIM, NP);
}

// Round 11
// 413.773 us; speedup vs baseline: 1.0876x; 1.0876x over previous
//
#include <hip/hip_runtime.h>
#include <math.h>

namespace {

constexpr int BT  = 8 * 4096;   // 32768 tokens
constexpr int DIM = 1024;       // model dim
constexpr int NE  = 64;         // experts
constexpr int NS  = 8;          // slots per expert
constexpr int NP  = NE * NS;    // 512 total slots
constexpr int HID = 256;

typedef float f32x4 __attribute__((ext_vector_type(4)));
typedef __bf16 bf16x8 __attribute__((ext_vector_type(8)));
typedef short s16x8 __attribute__((ext_vector_type(8)));

__device__ __forceinline__ ushort f2bf(float x) {
  union { float f; unsigned u; } a; a.f = x;
  unsigned r = a.u + 0x7FFFu + ((a.u >> 16) & 1u);  // RNE
  return (ushort)(r >> 16);
}
__device__ __forceinline__ float bf2f(ushort u) {
  union { unsigned u; float f; } a; a.u = (unsigned)u << 16;
  return a.f;
}

__device__ __forceinline__ void gload16(const void* g, void* l) {
  __builtin_amdgcn_global_load_lds(
      (const __attribute__((address_space(1))) void*)g,
      (__attribute__((address_space(3))) void*)l, 16, 0, 0);
}

// ---------------------------------------------------------------------------
// bf16 MFMA GEMM: C[M][N] = A[M][K](bf16 rm) @ Bt[N][K](bf16)^T
// Tile 256(M)x128(N), BK=64, 512 threads = 8 waves (4M x 2N), wave out 64x64.
// 3-buffer rotation (distinct static LDS arrays, compile-time identities):
//   tile t lives in buf(t%3); tile t+2 is staged DURING block t into
//   buf((t+2)%3) == buf freed at block t's entry barrier. One s_barrier and
//   one counted s_waitcnt vmcnt(6) per K-tile; no intra-block barriers —
//   waves free-run (m233: the 2-phase stage+vmcnt+barrier envelope was the
//   ~72% structural overhead; here it is amortized over 256 MFMA/CU-iter).
// LDS XOR swizzle (T2, rule #21 both-sides): element ^= (row&7)<<3, applied
// to the per-lane GLOBAL source of global_load_lds (LDS dest stays linear)
// and to the ds_read address — b128 reads of 16 rows x 128B become 2-way
// (free) instead of 16-way.
// ---------------------------------------------------------------------------
template <bool ATOMIC, bool OBF>
__global__ __launch_bounds__(512) void k_gemm(const ushort* __restrict__ A,
                                              const ushort* __restrict__ Bt,
                                              void* __restrict__ Cv,
                                              int K, int N, int kchunk) {
  __shared__ __align__(16) ushort As0[256 * 64];
  __shared__ __align__(16) ushort As1[256 * 64];
  __shared__ __align__(16) ushort As2[256 * 64];
  __shared__ __align__(16) ushort Bs0[128 * 64];
  __shared__ __align__(16) ushort Bs1[128 * 64];
  __shared__ __align__(16) ushort Bs2[128 * 64];

  const int tid = threadIdx.x;
  const int wid = tid >> 6;
  const int lane = tid & 63;

  // T1 XCD-chunked swizzle (bijective: nwg % 8 == 0)
  const int gx = gridDim.x, gy = gridDim.y;
  int wg = (blockIdx.z * gy + blockIdx.y) * gx + blockIdx.x;
  const int nwg = gx * gy * gridDim.z;
  wg = (wg & 7) * (nwg >> 3) + (wg >> 3);
  const int bx = wg % gx;
  const int rest = wg / gx;
  const int by = rest % gy;
  const int bz = rest / gy;

  const int n0 = bx * 128;
  const int m0 = by * 256;
  const int kb = bz * kchunk;

  // staging geometry: per gload16, wave w writes 8 rows (1KB) linearly.
  // lane l -> row_in_chunk = l>>3, swizzled col elems = ((l&7)^(l>>3))*8
  const int w8 = wid * 8;
  const int lr = lane >> 3;
  const int ks = (((lane & 7) ^ lr) * 8);
  const ushort* Asrc = A + (size_t)(m0 + w8 + lr) * K + ks;
  const ushort* Bsrc = Bt + (size_t)(n0 + w8 + lr) * K + ks;

  // fragment geometry
  const int wm64 = (wid >> 1) * 64;  // wave M-slice
  const int wn64 = (wid & 1) * 64;   // wave N-slice
  const int fr = lane & 15;
  const int fq = lane >> 4;
  const int fq8 = fq * 8;
  const int frsw = (fr & 7) << 3;    // element-offset XOR within 64-elem row

  f32x4 acc[4][4];
#pragma unroll
  for (int i = 0; i < 4; ++i)
#pragma unroll
    for (int j = 0; j < 4; ++j) acc[i][j] = (f32x4){0.f, 0.f, 0.f, 0.f};

  const int nt = kchunk / 64;

#define STAGE6(An_, Bn_, kt_)                                                   \
  do {                                                                          \
    _Pragma("unroll") for (int q = 0; q < 4; ++q)                               \
      gload16(Asrc + (size_t)(q * 64) * K + (kt_), (An_) + (q * 64 + w8) * 64); \
    _Pragma("unroll") for (int q = 0; q < 2; ++q)                               \
      gload16(Bsrc + (size_t)(q * 64) * K + (kt_), (Bn_) + (q * 64 + w8) * 64); \
  } while (0)

#define LD(B_, r_, h_)                                                          \
  __builtin_bit_cast(bf16x8, *(const s16x8*)((B_) + (size_t)(r_) * 64 +         \
                                             (((h_) * 32 + fq8) ^ frsw)))

#define GBLOCK(Ab_, Bb_, An_, Bn_, tt_)                                         \
  do {                                                                          \
    if ((tt_) + 1 < nt) asm volatile("s_waitcnt vmcnt(6)" ::: "memory");        \
    else                asm volatile("s_waitcnt vmcnt(0)" ::: "memory");        \
    __builtin_amdgcn_sched_barrier(0);                                          \
    __builtin_amdgcn_s_barrier();                                               \
    __builtin_amdgcn_sched_barrier(0);                                          \
    if ((tt_) + 2 < nt) STAGE6(An_, Bn_, kb + ((tt_) + 2) * 64);                \
    bf16x8 bfr_[4][2];                                                          \
    _Pragma("unroll") for (int n = 0; n < 4; ++n) {                             \
      bfr_[n][0] = LD(Bb_, wn64 + n * 16 + fr, 0);                              \
      bfr_[n][1] = LD(Bb_, wn64 + n * 16 + fr, 1);                              \
    }                                                                           \
    _Pragma("unroll") for (int m = 0; m < 4; ++m) {                             \
      bf16x8 a0_ = LD(Ab_, wm64 + m * 16 + fr, 0);                              \
      bf16x8 a1_ = LD(Ab_, wm64 + m * 16 + fr, 1);                              \
      __builtin_amdgcn_s_setprio(1);                                            \
      _Pragma("unroll") for (int n = 0; n < 4; ++n)                             \
        acc[m][n] = __builtin_amdgcn_mfma_f32_16x16x32_bf16(a0_, bfr_[n][0],    \
                                                            acc[m][n], 0, 0, 0);\
      _Pragma("unroll") for (int n = 0; n < 4; ++n)                             \
        acc[m][n] = __builtin_amdgcn_mfma_f32_16x16x32_bf16(a1_, bfr_[n][1],    \
                                                            acc[m][n], 0, 0, 0);\
      __builtin_amdgcn_s_setprio(0);                                            \
    }                                                                           \
  } while (0)

  // prologue: tiles 0 -> buf0, 1 -> buf1 (12 loads in flight)
  STAGE6(As0, Bs0, kb);
  STAGE6(As1, Bs1, kb + 64);
  int t = 0;
  for (; t + 3 <= nt; t += 3) {
    GBLOCK(As0, Bs0, As2, Bs2, t);
    GBLOCK(As1, Bs1, As0, Bs0, t + 1);
    GBLOCK(As2, Bs2, As1, Bs1, t + 2);
  }
  if (t < nt) { GBLOCK(As0, Bs0, As2, Bs2, t); ++t; }
  if (t < nt) { GBLOCK(As1, Bs1, As0, Bs0, t); ++t; }
#undef GBLOCK
#undef LD
#undef STAGE6

  // C/D layout: col = lane&15, row = (lane>>4)*4 + reg   [m89-verified]
  if (OBF) {
    ushort* Cb = (ushort*)Cv + (size_t)(m0 + wm64 + fq * 4) * N + n0 + wn64 + fr;
#pragma unroll
    for (int m = 0; m < 4; ++m)
#pragma unroll
      for (int n = 0; n < 4; ++n)
#pragma unroll
        for (int r = 0; r < 4; ++r)
          Cb[(size_t)(m * 16 + r) * N + n * 16] = f2bf(acc[m][n][r]);
  } else {
    float* Cb = (float*)Cv + (size_t)(m0 + wm64 + fq * 4) * N + n0 + wn64 + fr;
#pragma unroll
    for (int m = 0; m < 4; ++m)
#pragma unroll
      for (int n = 0; n < 4; ++n)
#pragma unroll
        for (int r = 0; r < 4; ++r) {
          float* p = Cb + (size_t)(m * 16 + r) * N + n * 16;
          if (ATOMIC) atomicAdd(p, acc[m][n][r]);
          else *p = acc[m][n][r];
        }
  }
}

// ---------------------------------------------------------------------------
// fp32 [R][C] -> bf16 rowmajor and/or bf16 transposed, 64x64 tiles.
// ---------------------------------------------------------------------------
template <bool ROWM, bool TRANSP>
__global__ __launch_bounds__(256) void k_cvt(const float* __restrict__ X,
                                             ushort* __restrict__ Yrm,
                                             ushort* __restrict__ Yt,
                                             int Rr, int Cc) {
  __shared__ ushort tT[64][66];
  const int tid = threadIdx.x;
  const int r0 = blockIdx.x * 64, c0 = blockIdx.y * 64;
#pragma unroll
  for (int i = 0; i < 4; ++i) {
    const int idx = i * 256 + tid;
    const int r = idx >> 4, c4 = (idx & 15) * 4;
    float4 v = *(const float4*)(X + (size_t)(r0 + r) * Cc + c0 + c4);
    ushort u0 = f2bf(v.x), u1 = f2bf(v.y), u2 = f2bf(v.z), u3 = f2bf(v.w);
    if (ROWM) {
      ushort4 o = make_ushort4(u0, u1, u2, u3);
      *(ushort4*)(Yrm + (size_t)(r0 + r) * Cc + c0 + c4) = o;
    }
    if (TRANSP) {
      tT[c4 + 0][r] = u0; tT[c4 + 1][r] = u1;
      tT[c4 + 2][r] = u2; tT[c4 + 3][r] = u3;
    }
  }
  if (TRANSP) {
    __syncthreads();
#pragma unroll
    for (int i = 0; i < 2; ++i) {
      const int idx = i * 256 + tid;
      const int c = idx >> 3, r8 = (idx & 7) * 8;
      s16x8 o;
#pragma unroll
      for (int j = 0; j < 8; ++j) o[j] = (short)tT[c][r8 + j];
      *(s16x8*)(Yt + (size_t)(c0 + c) * Rr + r0 + r8) = o;
    }
  }
}

// ---------------------------------------------------------------------------
// Column softmax stats over bf16 mat. Block: 256 rows x all 512 cols.
// ---------------------------------------------------------------------------
__global__ __launch_bounds__(256) void k_colpart(const ushort* __restrict__ mat,
                                                 float* __restrict__ pm,
                                                 float* __restrict__ pz) {
  const int c8 = (threadIdx.x & 63) * 8;
  const int rq = threadIdx.x >> 6;
  const int r0 = blockIdx.x * 256;
  float m[8], z[8];
#pragma unroll
  for (int j = 0; j < 8; ++j) { m[j] = -INFINITY; z[j] = 0.f; }
  for (int r = r0 + rq; r < r0 + 256; r += 4) {
    s16x8 v = *(const s16x8*)(mat + (size_t)r * NP + c8);
#pragma unroll
    for (int j = 0; j < 8; ++j) {
      float f = bf2f((ushort)v[j]);
      float mm = fmaxf(m[j], f);
      z[j] = z[j] * __expf(m[j] - mm) + __expf(f - mm);
      m[j] = mm;
    }
  }
  __shared__ float sm[4][NP], sz[4][NP];
#pragma unroll
  for (int j = 0; j < 8; ++j) { sm[rq][c8 + j] = m[j]; sz[rq][c8 + j] = z[j]; }
  __syncthreads();
  if (rq == 0) {
#pragma unroll
    for (int j = 0; j < 8; ++j) {
      float mj = m[j], zj = z[j];
      for (int q = 1; q < 4; ++q) {
        float m2 = sm[q][c8 + j], z2 = sz[q][c8 + j];
        float mm = fmaxf(mj, m2);
        zj = zj * __expf(mj - mm) + z2 * __expf(m2 - mm);
        mj = mm;
      }
      pm[(size_t)blockIdx.x * NP + c8 + j] = mj;
      pz[(size_t)blockIdx.x * NP + c8 + j] = zj;
    }
  }
}

__global__ void k_colfinal(const float* __restrict__ pm, const float* __restrict__ pz,
                           float* __restrict__ colM, float* __restrict__ colIZ) {
  const int c = threadIdx.x;  // <<<1, NP>>>
  float m = -INFINITY, z = 0.f;
  for (int q = 0; q < BT / 256; ++q) {
    float m2 = pm[(size_t)q * NP + c], z2 = pz[(size_t)q * NP + c];
    float mm = fmaxf(m, m2);
    z = z * __expf(m - mm) + z2 * __expf(m2 - mm);
    m = mm;
  }
  colM[c] = m;
  colIZ[c] = 1.f / z;
}

// ---------------------------------------------------------------------------
// Row softmax stats over bf16 mat: one wave per token.
// ---------------------------------------------------------------------------
__global__ __launch_bounds__(256) void k_rowstats(const ushort* __restrict__ mat,
                                                  float* __restrict__ rowM,
                                                  float* __restrict__ rowIZ) {
  const int w = threadIdx.x >> 6;
  const int lane = threadIdx.x & 63;
  const int t = blockIdx.x * 4 + w;
  s16x8 v = *(const s16x8*)(mat + (size_t)t * NP + lane * 8);
  float f[8];
#pragma unroll
  for (int j = 0; j < 8; ++j) f[j] = bf2f((ushort)v[j]);
  float m = f[0];
#pragma unroll
  for (int j = 1; j < 8; ++j) m = fmaxf(m, f[j]);
#pragma unroll
  for (int o = 32; o; o >>= 1) m = fmaxf(m, __shfl_xor(m, o));
  float s = 0.f;
#pragma unroll
  for (int j = 0; j < 8; ++j) s += __expf(f[j] - m);
#pragma unroll
  for (int o = 32; o; o >>= 1) s += __shfl_xor(s, o);
  if (lane == 0) {
    rowM[t] = m;
    rowIZ[t] = 1.f / s;
  }
}

// ---------------------------------------------------------------------------
// Probabilities in bf16 from bf16 mat: Pc[t][s] and Pt[s][t]. 64x64 tiles.
// ---------------------------------------------------------------------------
__global__ __launch_bounds__(256) void k_probs(const ushort* __restrict__ mat,
                                               const float* __restrict__ colM,
                                               const float* __restrict__ colIZ,
                                               const float* __restrict__ rowM,
                                               const float* __restrict__ rowIZ,
                                               ushort* __restrict__ Pc,
                                               ushort* __restrict__ Pt) {
  __shared__ ushort tT[64][66];
  __shared__ float cm[64], cz[64], rm[64], rz[64];
  const int tid = threadIdx.x;
  const int t0 = blockIdx.x * 64, s0 = blockIdx.y * 64;
  if (tid < 64) {
    cm[tid] = colM[s0 + tid]; cz[tid] = colIZ[s0 + tid];
    rm[tid] = rowM[t0 + tid]; rz[tid] = rowIZ[t0 + tid];
  }
  __syncthreads();
#pragma unroll
  for (int i = 0; i < 2; ++i) {
    const int idx = i * 256 + tid;
    const int r = idx >> 3, c8 = (idx & 7) * 8;
    s16x8 v = *(const s16x8*)(mat + (size_t)(t0 + r) * NP + s0 + c8);
    const float mr = rm[r], zr = rz[r];
    s16x8 oc;
#pragma unroll
    for (int j = 0; j < 8; ++j) {
      float f = bf2f((ushort)v[j]);
      oc[j] = (short)f2bf(__expf(f - mr) * zr);
      tT[c8 + j][r] = f2bf(__expf(f - cm[c8 + j]) * cz[c8 + j]);
    }
    *(s16x8*)(Pc + (size_t)(t0 + r) * NP + s0 + c8) = oc;
  }
  __syncthreads();
#pragma unroll
  for (int i = 0; i < 2; ++i) {
    const int idx = i * 256 + tid;
    const int c = idx >> 3, r8 = (idx & 7) * 8;
    s16x8 o;
#pragma unroll
    for (int j = 0; j < 8; ++j) o[j] = (short)tT[c][r8 + j];
    *(s16x8*)(Pt + (size_t)(s0 + c) * BT + t0 + r8) = o;
  }
}

// ---------------------------------------------------------------------------
// Expert MLP layer (fp32, weight-streaming, memory-bound)
// ---------------------------------------------------------------------------
template <int K, int N, bool RELU>
__global__ __launch_bounds__(256) void k_mlp(const float* __restrict__ X,
                                             const float* __restrict__ W,
                                             const float* __restrict__ bias,
                                             float* __restrict__ Y) {
  __shared__ float xs[NS * K];
  const int tid = threadIdx.x;
  const int e = blockIdx.x;
  const float4* src = (const float4*)(X + (size_t)e * NS * K);
  float4* dst = (float4*)xs;
  constexpr int NV = (NS * K) / (4 * 256);
#pragma unroll
  for (int i = 0; i < NV; ++i) dst[tid + i * 256] = src[tid + i * 256];
  __syncthreads();
  const int j = blockIdx.y * 64 + (tid & 63);
  const int pr = tid >> 6;
  const float* w = W + (size_t)e * K * N + j;
  const float* x0 = xs + pr * K;
  const float* x1 = xs + (pr + 4) * K;
  float a0 = 0.f, a1 = 0.f;
#pragma unroll 8
  for (int k = 0; k < K; ++k) {
    float wv = w[(size_t)k * N];
    a0 += x0[k] * wv;
    a1 += x1[k] * wv;
  }
  const float bb = bias[(size_t)e * N + j];
  a0 += bb;
  a1 += bb;
  if (RELU) {
    a0 = fmaxf(a0, 0.f);
    a1 = fmaxf(a1, 0.f);
  }
  Y[((size_t)e * NS + pr) * N + j] = a0;
  Y[((size_t)e * NS + pr + 4) * N + j] = a1;
}

}  // namespace

extern "C" void kernel_launch(void* const* d_in, const int* in_sizes, int n_in,
                              void* d_out, int out_size, void* d_ws, size_t ws_size,
                              hipStream_t stream) {
  const float* tokens = (const float*)d_in[0];  // [BT, DIM]
  const float* em     = (const float*)d_in[1];  // [DIM, NP]
  const float* W1     = (const float*)d_in[2];
  const float* b1     = (const float*)d_in[3];
  const float* W2     = (const float*)d_in[4];
  const float* b2     = (const float*)d_in[5];
  const float* W3     = (const float*)d_in[6];
  const float* b3     = (const float*)d_in[7];
  float* out = (float*)d_out;

  char* w = (char*)d_ws;
  ushort* matb      = (ushort*)w; w += (size_t)BT * NP * 2;    // 32MB bf16 logits
  ushort* tokens_bf = (ushort*)w; w += (size_t)BT * DIM * 2;   // 64MB
  ushort* tokT      = (ushort*)w; w += (size_t)DIM * BT * 2;   // 64MB
  ushort* Pt        = (ushort*)w; w += (size_t)NP * BT * 2;    // 33.5MB
  ushort* Pc        = (ushort*)w; w += (size_t)BT * NP * 2;    // 33.5MB
  ushort* emT       = (ushort*)w; w += (size_t)NP * DIM * 2;
  ushort* yhatT     = (ushort*)w; w += (size_t)DIM * NP * 2;
  float*  pm        = (float*)w;  w += (size_t)(BT / 256) * NP * 4;
  float*  pz        = (float*)w;  w += (size_t)(BT / 256) * NP * 4;
  float*  colM      = (float*)w;  w += NP * 4;
  float*  colIZ     = (float*)w;  w += NP * 4;
  float*  rowM      = (float*)w;  w += BT * 4;
  float*  rowIZ     = (float*)w;  w += BT * 4;
  float*  xhat      = (float*)w;  w += (size_t)NP * DIM * 4;
  float*  h1        = (float*)w;  w += (size_t)NP * HID * 4;
  float*  h2        = (float*)w;  w += (size_t)NP * HID * 4;
  float*  yhat      = (float*)w;  w += (size_t)NP * DIM * 4;
  (void)ws_size; (void)in_sizes; (void)n_in; (void)out_size;

  // prep: one pass over fp32 tokens -> rowmajor bf16 + transposed bf16
  k_cvt<true, true><<<dim3(BT / 64, DIM / 64), 256, 0, stream>>>(tokens, tokens_bf, tokT, BT, DIM);
  k_cvt<false, true><<<dim3(DIM / 64, NP / 64), 256, 0, stream>>>(em, nullptr, emT, DIM, NP);
  // 1. routing logits (bf16 out): 256x128 tile, 3-buf deep pipeline
  //    grid (N/128=4, M/256=128) = 512 wgs
  k_gemm<false, true><<<dim3(NP / 128, BT / 256, 1), 512, 0, stream>>>(tokens_bf, emT, matb, DIM, NP, DIM);
  // 2. softmax stats
  k_colpart<<<BT / 256, 256, 0, stream>>>(matb, pm, pz);
  k_colfinal<<<1, NP, 0, stream>>>(pm, pz, colM, colIZ);
  k_rowstats<<<BT / 4, 256, 0, stream>>>(matb, rowM, rowIZ);
  // 3. probabilities in bf16 (Pc rowmajor, Pt transposed)
  k_probs<<<dim3(BT / 64, NP / 64), 256, 0, stream>>>(matb, colM, colIZ, rowM, rowIZ, Pc, Pt);
  // 4. dispatch: xhat = Pt @ tokens  (split-K 16, fp32 atomics)
  //    grid (DIM/128=8, NP/256=2, 16) = 256 wgs, kchunk = 2048 -> nt = 32
  hipMemsetAsync(xhat, 0, (size_t)NP * DIM * 4, stream);
  k_gemm<true, false><<<dim3(DIM / 128, NP / 256, 16), 512, 0, stream>>>(Pt, tokT, xhat, BT, DIM, BT / 16);
  // 5. expert MLPs (fp32)
  k_mlp<DIM, HID, true><<<dim3(NE, HID / 64), 256, 0, stream>>>(xhat, W1, b1, h1);
  k_mlp<HID, HID, true><<<dim3(NE, HID / 64), 256, 0, stream>>>(h1, W2, b2, h2);
  k_mlp<HID, DIM, false><<<dim3(NE, DIM / 64), 256, 0, stream>>>(h2, W3, b3, yhat);
  k_cvt<false, true><<<dim3(NP / 64, DIM / 64), 256, 0, stream>>>(yhat, nullptr, yhatT, NP, DIM);
  // 6. combine: out = Pc @ yhat   grid (8, 128) = 1024 wgs, nt = 8
  k_gemm<false, false><<<dim3(DIM / 128, BT / 256, 1), 512, 0, stream>>>(Pc, yhatT, out, NP, DIM, NP);
}